// Round 4
// baseline (1140.501 us; speedup 1.0000x reference)
//
#include <hip/hip_runtime.h>
#include <math.h>

// AxileAttention: out = softmax((X@Wq+bq)*(X@Wk+bk), -1) * (X@Wv+bv), per (b,c).
// B=8 C=64 H=256 W=256, fp32 in/out.
//
// Round 4: split-f16 MFMA rewrite.
//  - q,k GEMMs: x,w split into f16 hi+lo; 3 MFMA products (hh, lh, hl) -> ~2^-22 rel err.
//  - v GEMM: single f16 (enters output linearly; err ~6e-3 << 1.4 threshold).
//  - block = 512 thr (8 waves), owns (b, c, 128 rows); waves tile 2(M) x 4(N);
//    wave tile 64x64 per matrix, mfma_f32_32x32x16_f16, acc = 192 VGPR.
//  - per k16 chunk: block stages W (fp32->hi/lo f16 frags) + X into LDS (48 KB),
//    2 barriers (m97-style). Conversion VALU overlaps MFMA (separate pipes).
//  - softmax: C-layout in-register shfl reduce over 32 lanes + 2-stage LDS combine.
//  - blk%8 == c%8 pins each channel's weight stream to one XCD's L2.

#define Bn 8
#define Cn 64
#define Hn 256
#define Wn 256

typedef _Float16 f16x8 __attribute__((ext_vector_type(8)));
typedef _Float16 f16x4 __attribute__((ext_vector_type(4)));
typedef float    f32x16 __attribute__((ext_vector_type(16)));

#define MFMA(a, b, c) __builtin_amdgcn_mfma_f32_32x32x16_f16((a), (b), (c), 0, 0, 0)

// LDS layout (48 KB):
//   B planes p=0..4 (q_hi,q_lo,k_hi,k_lo,v_hi): p*8192 + ntile*1024 + lane*16
//   A planes p=0..1 (hi,lo):          40960 + p*4096 + mtile*1024 + lane*16
#define LDS_A 40960

__global__ __launch_bounds__(512, 2) void axile_attn_mfma(
    const float* __restrict__ x,
    const float* __restrict__ wq,
    const float* __restrict__ wk,
    const float* __restrict__ wv,
    const float* __restrict__ bq,
    const float* __restrict__ bk,
    const float* __restrict__ bv,
    float* __restrict__ out)
{
    __shared__ __align__(16) char lds[49152];

    const int tid  = threadIdx.x;
    const int wave = tid >> 6;
    const int lane = tid & 63;
    const int h    = lane >> 5;    // lane half (k-group / row-group)
    const int l31  = lane & 31;

    // blk = j*64 + c, j = b*2 + htile  ->  blk%8 == c%8 (XCD affinity per channel)
    const int blk = blockIdx.x;
    const int c   = blk & 63;
    const int j   = blk >> 6;
    const int b   = j >> 1;
    const int h0  = (j & 1) * 128;

    const int mrow = wave >> 2;    // 0..1 : which 64-row half
    const int ncol = wave & 3;     // 0..3 : which 64-col strip

    const float* xbase = x + ((size_t)(b * Cn + c) * Hn + h0) * Wn;
    const float* w_q = wq + (size_t)c * Wn * Wn;
    const float* w_k = wk + (size_t)c * Wn * Wn;
    const float* w_v = wv + (size_t)c * Wn * Wn;

    f32x16 accq[2][2], acck[2][2], accv[2][2];
#pragma unroll
    for (int mt = 0; mt < 2; ++mt)
#pragma unroll
        for (int nt = 0; nt < 2; ++nt)
#pragma unroll
            for (int r = 0; r < 16; ++r) {
                accq[mt][nt][r] = 0.f;
                acck[mt][nt][r] = 0.f;
                accv[mt][nt][r] = 0.f;
            }

    for (int kt = 0; kt < 16; ++kt) {
        const int k0 = kt * 16;
        __syncthreads();

        // ---- stage W: thread job = (kg = tid>>8, n = tid&255) for each matrix ----
        {
            const int kg    = tid >> 8;       // k-group of 8
            const int n     = tid & 255;
            const int ntile = n >> 5;
            const int lc    = (kg << 5) | (n & 31);   // frag lane id
            const char* dstbase = lds + ntile * 1024 + lc * 16;
#pragma unroll
            for (int mat = 0; mat < 3; ++mat) {
                const float* Wp = (mat == 0) ? w_q : (mat == 1) ? w_k : w_v;
                float w8[8];
#pragma unroll
                for (int r = 0; r < 8; ++r)
                    w8[r] = Wp[(size_t)(k0 + kg * 8 + r) * Wn + n];
                f16x8 hi8, lo8;
#pragma unroll
                for (int r = 0; r < 8; ++r) {
                    _Float16 hv = (_Float16)w8[r];
                    hi8[r] = hv;
                    lo8[r] = (_Float16)(w8[r] - (float)hv);
                }
                *(f16x8*)((char*)dstbase + (mat * 2) * 8192) = hi8;
                if (mat < 2)
                    *(f16x8*)((char*)dstbase + (mat * 2 + 1) * 8192) = lo8;
            }
        }
        // ---- stage A: thread job = (m = tid>>2, kq = tid&3), 4 consecutive k ----
        {
            const int m  = tid >> 2;          // 0..127
            const int kq = tid & 3;
            const float4 xx = *(const float4*)(xbase + (size_t)m * Wn + k0 + kq * 4);
            f16x4 hi4, lo4;
            {
                _Float16 t0 = (_Float16)xx.x; hi4[0] = t0; lo4[0] = (_Float16)(xx.x - (float)t0);
                _Float16 t1 = (_Float16)xx.y; hi4[1] = t1; lo4[1] = (_Float16)(xx.y - (float)t1);
                _Float16 t2 = (_Float16)xx.z; hi4[2] = t2; lo4[2] = (_Float16)(xx.z - (float)t2);
                _Float16 t3 = (_Float16)xx.w; hi4[3] = t3; lo4[3] = (_Float16)(xx.w - (float)t3);
            }
            const int mtile = m >> 5;
            const int lc    = ((kq >> 1) << 5) | (m & 31);
            const int boff  = (kq & 1) * 8;
            *(f16x4*)(lds + LDS_A + 0 * 4096 + mtile * 1024 + lc * 16 + boff) = hi4;
            *(f16x4*)(lds + LDS_A + 1 * 4096 + mtile * 1024 + lc * 16 + boff) = lo4;
        }
        __syncthreads();

        // ---- compute ----
        f16x8 ah[2], al[2];
#pragma unroll
        for (int mt = 0; mt < 2; ++mt) {
            const int mtile = mrow * 2 + mt;
            ah[mt] = *(const f16x8*)(lds + LDS_A + mtile * 1024 + lane * 16);
            al[mt] = *(const f16x8*)(lds + LDS_A + 4096 + mtile * 1024 + lane * 16);
        }
#pragma unroll
        for (int nt = 0; nt < 2; ++nt) {
            const int ntile = ncol * 2 + nt;
            const char* bb = lds + ntile * 1024 + lane * 16;
            f16x8 bqh = *(const f16x8*)(bb + 0 * 8192);
            f16x8 bql = *(const f16x8*)(bb + 1 * 8192);
            f16x8 bkh = *(const f16x8*)(bb + 2 * 8192);
            f16x8 bkl = *(const f16x8*)(bb + 3 * 8192);
            f16x8 bvh = *(const f16x8*)(bb + 4 * 8192);
#pragma unroll
            for (int mt = 0; mt < 2; ++mt) {
                accq[mt][nt] = MFMA(ah[mt], bqh, accq[mt][nt]);
                accq[mt][nt] = MFMA(al[mt], bqh, accq[mt][nt]);
                accq[mt][nt] = MFMA(ah[mt], bql, accq[mt][nt]);
                acck[mt][nt] = MFMA(ah[mt], bkh, acck[mt][nt]);
                acck[mt][nt] = MFMA(al[mt], bkh, acck[mt][nt]);
                acck[mt][nt] = MFMA(ah[mt], bkl, acck[mt][nt]);
                accv[mt][nt] = MFMA(ah[mt], bvh, accv[mt][nt]);
            }
        }
    }
    __syncthreads();   // staging LDS dead; reuse for reductions

    float* part    = (float*)lds;            // [128 rows][4 ncol]
    float* combmax = (float*)(lds + 2048);   // [128]
    float* combsum = (float*)(lds + 2560);   // [128]

    // ---- bias add; s = q*k (into accq); v (into accv) ----
#pragma unroll
    for (int mt = 0; mt < 2; ++mt)
#pragma unroll
        for (int nt = 0; nt < 2; ++nt)
#pragma unroll
            for (int r = 0; r < 16; ++r) {
                const int rl = (r & 3) + 8 * (r >> 2) + 4 * h;
                const int hh = h0 + mrow * 64 + mt * 32 + rl;
                const int vv = ncol * 64 + nt * 32 + l31;
                const size_t bidx = ((size_t)c * Hn + hh) * Wn + vv;
                const float qv = accq[mt][nt][r] + bq[bidx];
                const float kv = acck[mt][nt][r] + bk[bidx];
                const float vx = accv[mt][nt][r] + bv[bidx];
                accq[mt][nt][r] = qv * kv;
                accv[mt][nt][r] = vx;
            }

    // ---- row max: 32-lane shfl reduce, predicated LDS write per (mt,r) ----
#pragma unroll
    for (int mt = 0; mt < 2; ++mt)
#pragma unroll
        for (int r = 0; r < 16; ++r) {
            float m2 = fmaxf(accq[mt][0][r], accq[mt][1][r]);
#pragma unroll
            for (int off = 16; off > 0; off >>= 1)
                m2 = fmaxf(m2, __shfl_xor(m2, off, 64));
            if ((lane & 15) == r && ((lane >> 4) & 1) == mt) {
                const int rl  = (r & 3) + 8 * (r >> 2) + 4 * h;
                const int row = mrow * 64 + mt * 32 + rl;
                part[row * 4 + ncol] = m2;
            }
        }
    __syncthreads();
    if (tid < 128)
        combmax[tid] = fmaxf(fmaxf(part[tid * 4 + 0], part[tid * 4 + 1]),
                             fmaxf(part[tid * 4 + 2], part[tid * 4 + 3]));
    __syncthreads();

    // ---- exp + row sum (e into acck) ----
#pragma unroll
    for (int mt = 0; mt < 2; ++mt)
#pragma unroll
        for (int r = 0; r < 16; ++r) {
            const int rl  = (r & 3) + 8 * (r >> 2) + 4 * h;
            const int row = mrow * 64 + mt * 32 + rl;
            const float mx = combmax[row];
            const float e0 = __expf(accq[mt][0][r] - mx);
            const float e1 = __expf(accq[mt][1][r] - mx);
            acck[mt][0][r] = e0;
            acck[mt][1][r] = e1;
            float ps = e0 + e1;
#pragma unroll
            for (int off = 16; off > 0; off >>= 1)
                ps += __shfl_xor(ps, off, 64);
            if ((lane & 15) == r && ((lane >> 4) & 1) == mt)
                part[row * 4 + ncol] = ps;
        }
    __syncthreads();
    if (tid < 128)
        combsum[tid] = (part[tid * 4 + 0] + part[tid * 4 + 1]) +
                       (part[tid * 4 + 2] + part[tid * 4 + 3]);
    __syncthreads();

    // ---- out = e * v / sum ----
    float* obase = out + ((size_t)(b * Cn + c) * Hn) * Wn;
#pragma unroll
    for (int mt = 0; mt < 2; ++mt)
#pragma unroll
        for (int r = 0; r < 16; ++r) {
            const int rl  = (r & 3) + 8 * (r >> 2) + 4 * h;
            const int row = mrow * 64 + mt * 32 + rl;
            const float inv = 1.0f / combsum[row];
            const int hh = h0 + row;
#pragma unroll
            for (int nt = 0; nt < 2; ++nt) {
                const int vv = ncol * 64 + nt * 32 + l31;
                obase[(size_t)hh * Wn + vv] = acck[mt][nt][r] * accv[mt][nt][r] * inv;
            }
        }
}

extern "C" void kernel_launch(void* const* d_in, const int* in_sizes, int n_in,
                              void* d_out, int out_size, void* d_ws, size_t ws_size,
                              hipStream_t stream) {
    (void)in_sizes; (void)n_in; (void)out_size; (void)d_ws; (void)ws_size;
    const float* x  = (const float*)d_in[0];
    const float* wq = (const float*)d_in[1];
    const float* wk = (const float*)d_in[2];
    const float* wv = (const float*)d_in[3];
    const float* bq = (const float*)d_in[4];
    const float* bk = (const float*)d_in[5];
    const float* bv = (const float*)d_in[6];
    float* out = (float*)d_out;

    dim3 grid(Bn * 2 * Cn);   // 1024 blocks: blk = (b*2+ht)*64 + c
    dim3 block(512);
    hipLaunchKernelGGL(axile_attn_mfma, grid, block, 0, stream,
                       x, wq, wk, wv, bq, bk, bv, out);
}

// Round 6
// 547.426 us; speedup vs baseline: 2.0834x; 2.0834x over previous
//
#include <hip/hip_runtime.h>
#include <math.h>

// AxileAttention: out = softmax((X@Wq+bq)*(X@Wk+bk), -1) * (X@Wv+bv), per (b,c).
// B=8 C=64 H=256 W=256, fp32 in/out.
//
// Round 6 == Round 5 resubmitted (container infra failure, kernel never ran).
// Two-phase K-loop caps live accumulators at 128 regs (fixes R4's 590 MB
// accumulator-spill traffic):
//   phase 1: q,k (split-f16, 3-MFMA each) -> s=q*k -> softmax e (64 regs) + inv in LDS
//   phase 2: v (single f16) second K-pass, accv 64 regs; out = e*v*inv.
// Block 512 thr (8 waves) owns (b,c,128 rows); wave tile 64x64, mfma_f32_32x32x16_f16.

#define Bn 8
#define Cn 64
#define Hn 256
#define Wn 256

typedef _Float16 f16x8 __attribute__((ext_vector_type(8)));
typedef _Float16 f16x4 __attribute__((ext_vector_type(4)));
typedef float    f32x16 __attribute__((ext_vector_type(16)));

#define MFMA(a, b, c) __builtin_amdgcn_mfma_f32_32x32x16_f16((a), (b), (c), 0, 0, 0)

// LDS layout (44 KB):
//   A hi:  [0, 4096)        mtile*1024 + lane*16
//   A lo:  [4096, 8192)
//   B:     [8192, 40960)    plane p*8192 + ntile*1024 + lane*16
//          phase1 planes: 0=qh 1=ql 2=kh 3=kl; phase2: plane 0 = vh
//   smx:   [40960, 44032)   part[128][4], combmax[128], combsum[128]
#define LDS_ALO 4096
#define LDS_B   8192
#define LDS_SM  40960

__global__ __launch_bounds__(512, 2) void axile_attn_mfma2(
    const float* __restrict__ x,
    const float* __restrict__ wq,
    const float* __restrict__ wk,
    const float* __restrict__ wv,
    const float* __restrict__ bq,
    const float* __restrict__ bk,
    const float* __restrict__ bv,
    float* __restrict__ out)
{
    __shared__ __align__(16) char lds[44032];

    const int tid  = threadIdx.x;
    const int wave = tid >> 6;
    const int lane = tid & 63;
    const int h    = lane >> 5;
    const int l31  = lane & 31;

    const int blk = blockIdx.x;
    const int c   = blk & 63;
    const int j   = blk >> 6;
    const int b   = j >> 1;
    const int h0  = (j & 1) * 128;

    const int mrow = wave >> 2;    // 0..1
    const int ncol = wave & 3;     // 0..3

    const float* xbase = x + ((size_t)(b * Cn + c) * Hn + h0) * Wn;
    const float* w_q = wq + (size_t)c * Wn * Wn;
    const float* w_k = wk + (size_t)c * Wn * Wn;
    const float* w_v = wv + (size_t)c * Wn * Wn;

    // staging decomposition (shared by both phases)
    const int kg    = tid >> 8;          // 0..1  (k-group of 8)
    const int n     = tid & 255;
    const int ntW   = n >> 5;
    const int lcW   = (kg << 5) | (n & 31);
    const int am    = tid >> 2;          // 0..127
    const int akq   = tid & 3;
    const int amt   = am >> 5;
    const int alc   = ((akq >> 1) << 5) | (am & 31);
    const int aboff = (akq & 1) * 8;

    f32x16 accq[2][2], acck[2][2];
#pragma unroll
    for (int mt = 0; mt < 2; ++mt)
#pragma unroll
        for (int nt = 0; nt < 2; ++nt)
#pragma unroll
            for (int r = 0; r < 16; ++r) {
                accq[mt][nt][r] = 0.f;
                acck[mt][nt][r] = 0.f;
            }

    // ================= phase 1: q,k =================
    for (int kt = 0; kt < 16; ++kt) {
        const int k0 = kt * 16;
        __syncthreads();
        // stage Wq, Wk (hi+lo)
        {
            char* dst = lds + LDS_B + ntW * 1024 + lcW * 16;
#pragma unroll
            for (int mat = 0; mat < 2; ++mat) {
                const float* Wp = mat ? w_k : w_q;
                float w8[8];
#pragma unroll
                for (int r = 0; r < 8; ++r)
                    w8[r] = Wp[(size_t)(k0 + kg * 8 + r) * Wn + n];
                f16x8 hi8, lo8;
#pragma unroll
                for (int r = 0; r < 8; ++r) {
                    _Float16 hv = (_Float16)w8[r];
                    hi8[r] = hv;
                    lo8[r] = (_Float16)(w8[r] - (float)hv);
                }
                *(f16x8*)(dst + (mat * 2) * 8192) = hi8;
                *(f16x8*)(dst + (mat * 2 + 1) * 8192) = lo8;
            }
        }
        // stage X (hi+lo)
        {
            const float4 xx = *(const float4*)(xbase + (size_t)am * Wn + k0 + akq * 4);
            f16x4 hi4, lo4;
            _Float16 t0 = (_Float16)xx.x; hi4[0] = t0; lo4[0] = (_Float16)(xx.x - (float)t0);
            _Float16 t1 = (_Float16)xx.y; hi4[1] = t1; lo4[1] = (_Float16)(xx.y - (float)t1);
            _Float16 t2 = (_Float16)xx.z; hi4[2] = t2; lo4[2] = (_Float16)(xx.z - (float)t2);
            _Float16 t3 = (_Float16)xx.w; hi4[3] = t3; lo4[3] = (_Float16)(xx.w - (float)t3);
            *(f16x4*)(lds + amt * 1024 + alc * 16 + aboff) = hi4;
            *(f16x4*)(lds + LDS_ALO + amt * 1024 + alc * 16 + aboff) = lo4;
        }
        __syncthreads();

        f16x8 ah[2], al[2];
#pragma unroll
        for (int mt = 0; mt < 2; ++mt) {
            const int mtile = mrow * 2 + mt;
            ah[mt] = *(const f16x8*)(lds + mtile * 1024 + lane * 16);
            al[mt] = *(const f16x8*)(lds + LDS_ALO + mtile * 1024 + lane * 16);
        }
#pragma unroll
        for (int nt = 0; nt < 2; ++nt) {
            const int ntile = ncol * 2 + nt;
            const char* bb = lds + LDS_B + ntile * 1024 + lane * 16;
            f16x8 bqh = *(const f16x8*)(bb + 0 * 8192);
            f16x8 bql = *(const f16x8*)(bb + 1 * 8192);
            f16x8 bkh = *(const f16x8*)(bb + 2 * 8192);
            f16x8 bkl = *(const f16x8*)(bb + 3 * 8192);
#pragma unroll
            for (int mt = 0; mt < 2; ++mt) {
                accq[mt][nt] = MFMA(ah[mt], bqh, accq[mt][nt]);
                accq[mt][nt] = MFMA(al[mt], bqh, accq[mt][nt]);
                accq[mt][nt] = MFMA(ah[mt], bql, accq[mt][nt]);
                acck[mt][nt] = MFMA(ah[mt], bkh, acck[mt][nt]);
                acck[mt][nt] = MFMA(al[mt], bkh, acck[mt][nt]);
                acck[mt][nt] = MFMA(ah[mt], bkl, acck[mt][nt]);
            }
        }
    }

    float* part    = (float*)(lds + LDS_SM);          // [128][4]
    float* combmax = (float*)(lds + LDS_SM + 2048);   // [128]
    float* combsum = (float*)(lds + LDS_SM + 2560);   // [128]

    // ---- bias add; s = q*k into accq (acck dies here) ----
#pragma unroll
    for (int mt = 0; mt < 2; ++mt)
#pragma unroll
        for (int nt = 0; nt < 2; ++nt)
#pragma unroll
            for (int r = 0; r < 16; ++r) {
                const int rl = (r & 3) + 8 * (r >> 2) + 4 * h;
                const int hh = h0 + mrow * 64 + mt * 32 + rl;
                const int vv = ncol * 64 + nt * 32 + l31;
                const size_t bidx = ((size_t)c * Hn + hh) * Wn + vv;
                const float qv = accq[mt][nt][r] + bq[bidx];
                const float kv = acck[mt][nt][r] + bk[bidx];
                accq[mt][nt][r] = qv * kv;
            }

    // ---- row max ----
#pragma unroll
    for (int mt = 0; mt < 2; ++mt)
#pragma unroll
        for (int r = 0; r < 16; ++r) {
            float m2 = fmaxf(accq[mt][0][r], accq[mt][1][r]);
#pragma unroll
            for (int off = 16; off > 0; off >>= 1)
                m2 = fmaxf(m2, __shfl_xor(m2, off, 64));
            if ((lane & 15) == r && ((lane >> 4) & 1) == mt) {
                const int rl  = (r & 3) + 8 * (r >> 2) + 4 * h;
                const int row = mrow * 64 + mt * 32 + rl;
                part[row * 4 + ncol] = m2;
            }
        }
    __syncthreads();
    if (tid < 128)
        combmax[tid] = fmaxf(fmaxf(part[tid * 4 + 0], part[tid * 4 + 1]),
                             fmaxf(part[tid * 4 + 2], part[tid * 4 + 3]));
    __syncthreads();

    // ---- e = exp(s - mx) into accq; row sum ----
#pragma unroll
    for (int mt = 0; mt < 2; ++mt)
#pragma unroll
        for (int r = 0; r < 16; ++r) {
            const int rl  = (r & 3) + 8 * (r >> 2) + 4 * h;
            const int row = mrow * 64 + mt * 32 + rl;
            const float mx = combmax[row];
            const float e0 = __expf(accq[mt][0][r] - mx);
            const float e1 = __expf(accq[mt][1][r] - mx);
            accq[mt][0][r] = e0;
            accq[mt][1][r] = e1;
            float ps = e0 + e1;
#pragma unroll
            for (int off = 16; off > 0; off >>= 1)
                ps += __shfl_xor(ps, off, 64);
            if ((lane & 15) == r && ((lane >> 4) & 1) == mt)
                part[row * 4 + ncol] = ps;
        }
    __syncthreads();
    if (tid < 128)
        combsum[tid] = (part[tid * 4 + 0] + part[tid * 4 + 1]) +
                       (part[tid * 4 + 2] + part[tid * 4 + 3]);
    // (phase-2 first barrier covers the combsum visibility)

    // ================= phase 2: v =================
    f32x16 accv[2][2];
#pragma unroll
    for (int mt = 0; mt < 2; ++mt)
#pragma unroll
        for (int nt = 0; nt < 2; ++nt)
#pragma unroll
            for (int r = 0; r < 16; ++r)
                accv[mt][nt][r] = 0.f;

    for (int kt = 0; kt < 16; ++kt) {
        const int k0 = kt * 16;
        __syncthreads();
        // stage Wv (hi only) into B plane 0
        {
            char* dst = lds + LDS_B + ntW * 1024 + lcW * 16;
            float w8[8];
#pragma unroll
            for (int r = 0; r < 8; ++r)
                w8[r] = w_v[(size_t)(k0 + kg * 8 + r) * Wn + n];
            f16x8 hi8;
#pragma unroll
            for (int r = 0; r < 8; ++r)
                hi8[r] = (_Float16)w8[r];
            *(f16x8*)dst = hi8;
        }
        // stage X (hi only)
        {
            const float4 xx = *(const float4*)(xbase + (size_t)am * Wn + k0 + akq * 4);
            f16x4 hi4;
            hi4[0] = (_Float16)xx.x;
            hi4[1] = (_Float16)xx.y;
            hi4[2] = (_Float16)xx.z;
            hi4[3] = (_Float16)xx.w;
            *(f16x4*)(lds + amt * 1024 + alc * 16 + aboff) = hi4;
        }
        __syncthreads();

        f16x8 ah[2];
#pragma unroll
        for (int mt = 0; mt < 2; ++mt)
            ah[mt] = *(const f16x8*)(lds + (mrow * 2 + mt) * 1024 + lane * 16);
#pragma unroll
        for (int nt = 0; nt < 2; ++nt) {
            const int ntile = ncol * 2 + nt;
            f16x8 bvh = *(const f16x8*)(lds + LDS_B + ntile * 1024 + lane * 16);
#pragma unroll
            for (int mt = 0; mt < 2; ++mt)
                accv[mt][nt] = MFMA(ah[mt], bvh, accv[mt][nt]);
        }
    }

    // ---- out = e * (v + bv) / sum ----
    float* obase = out + ((size_t)(b * Cn + c) * Hn) * Wn;
#pragma unroll
    for (int mt = 0; mt < 2; ++mt)
#pragma unroll
        for (int r = 0; r < 16; ++r) {
            const int rl  = (r & 3) + 8 * (r >> 2) + 4 * h;
            const int row = mrow * 64 + mt * 32 + rl;
            const float inv = 1.0f / combsum[row];
            const int hh = h0 + row;
#pragma unroll
            for (int nt = 0; nt < 2; ++nt) {
                const int vv = ncol * 64 + nt * 32 + l31;
                const size_t bidx = ((size_t)c * Hn + hh) * Wn + vv;
                const float vx = accv[mt][nt][r] + bv[bidx];
                obase[(size_t)hh * Wn + vv] = accq[mt][nt][r] * vx * inv;
            }
        }
}

extern "C" void kernel_launch(void* const* d_in, const int* in_sizes, int n_in,
                              void* d_out, int out_size, void* d_ws, size_t ws_size,
                              hipStream_t stream) {
    (void)in_sizes; (void)n_in; (void)out_size; (void)d_ws; (void)ws_size;
    const float* x  = (const float*)d_in[0];
    const float* wq = (const float*)d_in[1];
    const float* wk = (const float*)d_in[2];
    const float* wv = (const float*)d_in[3];
    const float* bq = (const float*)d_in[4];
    const float* bk = (const float*)d_in[5];
    const float* bv = (const float*)d_in[6];
    float* out = (float*)d_out;

    dim3 grid(Bn * 2 * Cn);   // 1024 blocks: blk = (b*2+ht)*64 + c
    dim3 block(512);
    hipLaunchKernelGGL(axile_attn_mfma2, grid, block, 0, stream,
                       x, wq, wk, wv, bq, bk, bv, out);
}

// Round 7
// 533.955 us; speedup vs baseline: 2.1360x; 1.0252x over previous
//
#include <hip/hip_runtime.h>
#include <math.h>

// AxileAttention: out = softmax((X@Wq+bq)*(X@Wk+bk), -1) * (X@Wv+bv), per (b,c).
// B=8 C=64 H=256 W=256, fp32 in/out.
//
// Round 7: 256-thr blocks (4 waves, 64 rows), 2 blocks/CU for cross-block
// latency hiding (R6 was 1 block/CU -> barrier-serialized, MfmaUtil 13%).
// Two-phase K-loop (caps live acc at 128 regs, no spill):
//   phase 1: q,k (split-f16, 3-MFMA each) -> s=q*k -> softmax e (64 regs)
//   phase 2: v (single f16) second K-pass, accv 64 regs; out = e*(v+bv)*inv.
// Wave tile 64x64, mfma_f32_32x32x16_f16. Waves = 4 ncol strips.

#define Bn 8
#define Cn 64
#define Hn 256
#define Wn 256

typedef _Float16 f16x8 __attribute__((ext_vector_type(8)));
typedef _Float16 f16x4 __attribute__((ext_vector_type(4)));
typedef float    f32x16 __attribute__((ext_vector_type(16)));

#define MFMA(a, b, c) __builtin_amdgcn_mfma_f32_32x32x16_f16((a), (b), (c), 0, 0, 0)

// LDS layout (37.5 KB -> 2 blocks/CU):
//   A hi: [0,2048)       mtile*1024 + lane*16   (mtile 0..1)
//   A lo: [2048,4096)
//   B:    [4096,36864)   plane p*8192 + ntile*1024 + lane*16
//         phase1 planes: 0=qh 1=ql 2=kh 3=kl; phase2: plane 0 = vh
//   smx:  [36864,38400)  part[64][4] @0, combmax[64] @1024, combsum[64] @1280
#define LDS_ALO 2048
#define LDS_B   4096
#define LDS_SM  36864

__global__ __launch_bounds__(256, 2) void axile_attn_mfma3(
    const float* __restrict__ x,
    const float* __restrict__ wq,
    const float* __restrict__ wk,
    const float* __restrict__ wv,
    const float* __restrict__ bq,
    const float* __restrict__ bk,
    const float* __restrict__ bv,
    float* __restrict__ out)
{
    __shared__ __align__(16) char lds[38400];

    const int tid  = threadIdx.x;
    const int ncol = tid >> 6;     // wave id = column strip 0..3
    const int lane = tid & 63;
    const int h    = lane >> 5;
    const int l31  = lane & 31;

    // blk = j*64 + c  (c in low bits -> blk%8==c%8: XCD affinity per channel)
    const int blk = blockIdx.x;
    const int c   = blk & 63;
    const int j   = blk >> 6;      // 0..31 = b*4 + ht
    const int b   = j >> 2;
    const int h0  = (j & 3) * 64;

    const float* xbase = x + ((size_t)(b * Cn + c) * Hn + h0) * Wn;
    const float* w_q = wq + (size_t)c * Wn * Wn;
    const float* w_k = wk + (size_t)c * Wn * Wn;
    const float* w_v = wv + (size_t)c * Wn * Wn;

    // W staging: thread = column n (0..255), loads k=0..15 at that column.
    const int n    = tid;
    const int ntW  = n >> 5;
    const int nl   = n & 31;
    // X staging: thread = (row m = tid>>2, kq = tid&3) -> float4 of 4 k's.
    const int am    = tid >> 2;          // 0..63
    const int akq   = tid & 3;
    const int amt   = am >> 5;
    const int alc   = ((akq >> 1) << 5) | (am & 31);
    const int aboff = (akq & 1) * 8;

    f32x16 accq[2][2], acck[2][2];
#pragma unroll
    for (int mt = 0; mt < 2; ++mt)
#pragma unroll
        for (int nt = 0; nt < 2; ++nt)
#pragma unroll
            for (int r = 0; r < 16; ++r) {
                accq[mt][nt][r] = 0.f;
                acck[mt][nt][r] = 0.f;
            }

    // ================= phase 1: q,k =================
    for (int kt = 0; kt < 16; ++kt) {
        const int k0 = kt * 16;
        __syncthreads();
        // stage Wq, Wk (hi+lo): 16 k-rows per thread-column, coalesced per row
#pragma unroll
        for (int mat = 0; mat < 2; ++mat) {
            const float* Wp = mat ? w_k : w_q;
            float w16[16];
#pragma unroll
            for (int r = 0; r < 16; ++r)
                w16[r] = Wp[(size_t)(k0 + r) * Wn + n];
            char* dplane = lds + LDS_B + (mat * 2) * 8192 + ntW * 1024;
#pragma unroll
            for (int h2 = 0; h2 < 2; ++h2) {
                f16x8 hi8, lo8;
#pragma unroll
                for (int e = 0; e < 8; ++e) {
                    const float wv_ = w16[h2 * 8 + e];
                    _Float16 hv = (_Float16)wv_;
                    hi8[e] = hv;
                    lo8[e] = (_Float16)(wv_ - (float)hv);
                }
                const int fo = ((h2 << 5) | nl) * 16;
                *(f16x8*)(dplane + fo) = hi8;
                *(f16x8*)(dplane + 8192 + fo) = lo8;
            }
        }
        // stage X (hi+lo)
        {
            const float4 xx = *(const float4*)(xbase + (size_t)am * Wn + k0 + akq * 4);
            f16x4 hi4, lo4;
            _Float16 t0 = (_Float16)xx.x; hi4[0] = t0; lo4[0] = (_Float16)(xx.x - (float)t0);
            _Float16 t1 = (_Float16)xx.y; hi4[1] = t1; lo4[1] = (_Float16)(xx.y - (float)t1);
            _Float16 t2 = (_Float16)xx.z; hi4[2] = t2; lo4[2] = (_Float16)(xx.z - (float)t2);
            _Float16 t3 = (_Float16)xx.w; hi4[3] = t3; lo4[3] = (_Float16)(xx.w - (float)t3);
            *(f16x4*)(lds + amt * 1024 + alc * 16 + aboff) = hi4;
            *(f16x4*)(lds + LDS_ALO + amt * 1024 + alc * 16 + aboff) = lo4;
        }
        __syncthreads();

        f16x8 ah[2], al[2];
#pragma unroll
        for (int mt = 0; mt < 2; ++mt) {
            ah[mt] = *(const f16x8*)(lds + mt * 1024 + lane * 16);
            al[mt] = *(const f16x8*)(lds + LDS_ALO + mt * 1024 + lane * 16);
        }
#pragma unroll
        for (int nt = 0; nt < 2; ++nt) {
            const int ntile = ncol * 2 + nt;
            const char* bb = lds + LDS_B + ntile * 1024 + lane * 16;
            f16x8 bqh = *(const f16x8*)(bb + 0 * 8192);
            f16x8 bql = *(const f16x8*)(bb + 1 * 8192);
            f16x8 bkh = *(const f16x8*)(bb + 2 * 8192);
            f16x8 bkl = *(const f16x8*)(bb + 3 * 8192);
#pragma unroll
            for (int mt = 0; mt < 2; ++mt) {
                accq[mt][nt] = MFMA(ah[mt], bqh, accq[mt][nt]);
                accq[mt][nt] = MFMA(al[mt], bqh, accq[mt][nt]);
                accq[mt][nt] = MFMA(ah[mt], bql, accq[mt][nt]);
                acck[mt][nt] = MFMA(ah[mt], bkh, acck[mt][nt]);
                acck[mt][nt] = MFMA(al[mt], bkh, acck[mt][nt]);
                acck[mt][nt] = MFMA(ah[mt], bkl, acck[mt][nt]);
            }
        }
    }

    float* part    = (float*)(lds + LDS_SM);          // [64][4]
    float* combmax = (float*)(lds + LDS_SM + 1024);   // [64]
    float* combsum = (float*)(lds + LDS_SM + 1280);   // [64]

    // ---- bias add; s = q*k into accq (acck dies here) ----
#pragma unroll
    for (int mt = 0; mt < 2; ++mt)
#pragma unroll
        for (int nt = 0; nt < 2; ++nt)
#pragma unroll
            for (int r = 0; r < 16; ++r) {
                const int rl = (r & 3) + 8 * (r >> 2) + 4 * h;
                const int hh = h0 + mt * 32 + rl;
                const int vv = ncol * 64 + nt * 32 + l31;
                const size_t bidx = ((size_t)c * Hn + hh) * Wn + vv;
                const float qv = accq[mt][nt][r] + bq[bidx];
                const float kv = acck[mt][nt][r] + bk[bidx];
                accq[mt][nt][r] = qv * kv;
            }

    // ---- row max (reduce over 32-lane half; h stays separate) ----
#pragma unroll
    for (int mt = 0; mt < 2; ++mt)
#pragma unroll
        for (int r = 0; r < 16; ++r) {
            float m2 = fmaxf(accq[mt][0][r], accq[mt][1][r]);
#pragma unroll
            for (int off = 16; off > 0; off >>= 1)
                m2 = fmaxf(m2, __shfl_xor(m2, off, 64));
            if ((lane & 15) == r && ((lane >> 4) & 1) == mt) {
                const int rl  = (r & 3) + 8 * (r >> 2) + 4 * h;
                const int row = mt * 32 + rl;
                part[row * 4 + ncol] = m2;
            }
        }
    __syncthreads();
    if (tid < 64)
        combmax[tid] = fmaxf(fmaxf(part[tid * 4 + 0], part[tid * 4 + 1]),
                             fmaxf(part[tid * 4 + 2], part[tid * 4 + 3]));
    __syncthreads();

    // ---- e = exp(s - mx) into accq; row sum ----
#pragma unroll
    for (int mt = 0; mt < 2; ++mt)
#pragma unroll
        for (int r = 0; r < 16; ++r) {
            const int rl  = (r & 3) + 8 * (r >> 2) + 4 * h;
            const int row = mt * 32 + rl;
            const float mx = combmax[row];
            const float e0 = __expf(accq[mt][0][r] - mx);
            const float e1 = __expf(accq[mt][1][r] - mx);
            accq[mt][0][r] = e0;
            accq[mt][1][r] = e1;
            float ps = e0 + e1;
#pragma unroll
            for (int off = 16; off > 0; off >>= 1)
                ps += __shfl_xor(ps, off, 64);
            if ((lane & 15) == r && ((lane >> 4) & 1) == mt)
                part[row * 4 + ncol] = ps;
        }
    __syncthreads();
    if (tid < 64)
        combsum[tid] = (part[tid * 4 + 0] + part[tid * 4 + 1]) +
                       (part[tid * 4 + 2] + part[tid * 4 + 3]);
    // (phase-2 first barrier covers combsum visibility)

    // ================= phase 2: v =================
    f32x16 accv[2][2];
#pragma unroll
    for (int mt = 0; mt < 2; ++mt)
#pragma unroll
        for (int nt = 0; nt < 2; ++nt)
#pragma unroll
            for (int r = 0; r < 16; ++r)
                accv[mt][nt][r] = 0.f;

    for (int kt = 0; kt < 16; ++kt) {
        const int k0 = kt * 16;
        __syncthreads();
        // stage Wv (hi only) into B plane 0
        {
            float w16[16];
#pragma unroll
            for (int r = 0; r < 16; ++r)
                w16[r] = w_v[(size_t)(k0 + r) * Wn + n];
            char* dplane = lds + LDS_B + ntW * 1024;
#pragma unroll
            for (int h2 = 0; h2 < 2; ++h2) {
                f16x8 hi8;
#pragma unroll
                for (int e = 0; e < 8; ++e)
                    hi8[e] = (_Float16)w16[h2 * 8 + e];
                *(f16x8*)(dplane + ((h2 << 5) | nl) * 16) = hi8;
            }
        }
        // stage X (hi only)
        {
            const float4 xx = *(const float4*)(xbase + (size_t)am * Wn + k0 + akq * 4);
            f16x4 hi4;
            hi4[0] = (_Float16)xx.x;
            hi4[1] = (_Float16)xx.y;
            hi4[2] = (_Float16)xx.z;
            hi4[3] = (_Float16)xx.w;
            *(f16x4*)(lds + amt * 1024 + alc * 16 + aboff) = hi4;
        }
        __syncthreads();

        f16x8 ah[2];
#pragma unroll
        for (int mt = 0; mt < 2; ++mt)
            ah[mt] = *(const f16x8*)(lds + mt * 1024 + lane * 16);
#pragma unroll
        for (int nt = 0; nt < 2; ++nt) {
            const int ntile = ncol * 2 + nt;
            f16x8 bvh = *(const f16x8*)(lds + LDS_B + ntile * 1024 + lane * 16);
#pragma unroll
            for (int mt = 0; mt < 2; ++mt)
                accv[mt][nt] = MFMA(ah[mt], bvh, accv[mt][nt]);
        }
    }

    // ---- out = e * (v + bv) / sum ----
    float* obase = out + ((size_t)(b * Cn + c) * Hn) * Wn;
#pragma unroll
    for (int mt = 0; mt < 2; ++mt)
#pragma unroll
        for (int r = 0; r < 16; ++r) {
            const int rl  = (r & 3) + 8 * (r >> 2) + 4 * h;
            const int row = mt * 32 + rl;
            const float inv = 1.0f / combsum[row];
            const int hh = h0 + row;
#pragma unroll
            for (int nt = 0; nt < 2; ++nt) {
                const int vv = ncol * 64 + nt * 32 + l31;
                const size_t bidx = ((size_t)c * Hn + hh) * Wn + vv;
                const float vx = accv[mt][nt][r] + bv[bidx];
                obase[(size_t)hh * Wn + vv] = accq[mt][nt][r] * vx * inv;
            }
        }
}

extern "C" void kernel_launch(void* const* d_in, const int* in_sizes, int n_in,
                              void* d_out, int out_size, void* d_ws, size_t ws_size,
                              hipStream_t stream) {
    (void)in_sizes; (void)n_in; (void)out_size; (void)d_ws; (void)ws_size;
    const float* x  = (const float*)d_in[0];
    const float* wq = (const float*)d_in[1];
    const float* wk = (const float*)d_in[2];
    const float* wv = (const float*)d_in[3];
    const float* bq = (const float*)d_in[4];
    const float* bk = (const float*)d_in[5];
    const float* bv = (const float*)d_in[6];
    float* out = (float*)d_out;

    dim3 grid(Bn * 4 * Cn);   // 2048 blocks: blk = (b*4+ht)*64 + c
    dim3 block(256);
    hipLaunchKernelGGL(axile_attn_mfma3, grid, block, 0, stream,
                       x, wq, wk, wv, bq, bk, bv, out);
}